// Round 8
// baseline (703.924 us; speedup 1.0000x reference)
//
#include <hip/hip_runtime.h>
#include <math.h>

// Problem constants
#define B_    512
#define T_    256
#define DIN   64
#define DS    64
#define KK    128   // DIN + DS
#define NN    2048
#define DOUT  10

// Tiling: 256 WGs = NTILES(4) x BTILES(64), 512 thr (8 waves), 1 WG/CU.
// blockIdx -> (bt,nt) XCD-swizzled: clique (bt, nt=0..3) shares blockIdx%8
// -> same XCD under SPX round-robin (VERIFIED R2: FETCH 590->151MB).
// Exchange: dual-publish tagged u64 (tag+payload in ONE word -> every
// consumed word self-validates; R2 proved correctness of this scheme):
//   producer: sc0 stores to psqF (local L2) then agent mirror to psqA.
//   consumer: sc0 speculative + sentinel-slot spin (8B/lane/retry, 4x less
//   traffic than R2's convoying 32B polls), bounded -> R0 agent loop.
//   Sticky per-thread slowmode caps the broken-placement case at ~R0 speed.
#define NT      512
#define BT      8
#define NTILES  (NN / NT)      // 4
#define BTILES  (B_ / BT)      // 64
#define THREADS 512
#define NWG     (NTILES * BTILES)   // 256

// Workspace: psqA (agent, 2 bufs) | psqF (sc0 fast, 2 bufs) | EtSw | SdSw
#define PSQ_ELEMS  ((size_t)BTILES * NTILES * BT * DS)  // 131072 u64 per buffer
#define PSQF_OFF   (4 * PSQ_ELEMS)                      // float-word offset
#define ETSW_OFF   (8 * PSQ_ELEMS)
#define ETSW_F16   ((size_t)KK * NN)                    // 262144 f16 = 512 KB
#define SDSW_OFF   (ETSW_OFF + ETSW_F16 / 2)
#define SDSW_F16   ((size_t)NN * DS)                    // 131072 f16 = 256 KB

typedef _Float16 half8 __attribute__((ext_vector_type(8)));
typedef float    f32x4 __attribute__((ext_vector_type(4)));

__global__ __launch_bounds__(256) void pre_kernel(const float* __restrict__ enc,
                                                  const float* __restrict__ sd,
                                                  float* __restrict__ ws,
                                                  float* __restrict__ out) {
    size_t i = (size_t)blockIdx.x * blockDim.x + threadIdx.x;
    size_t stride = (size_t)gridDim.x * blockDim.x;
    // zero BOTH tagged regions (psqA + psqF); tag 0 never matches (tags >= 1)
    unsigned long long* psq = (unsigned long long*)ws;
    for (size_t x = i; x < 4 * PSQ_ELEMS; x += stride) psq[x] = 0ull;
    // EtSw: B-fragments, 8-wave ownership (R13-verified).
    _Float16* EtSw = (_Float16*)(ws + ETSW_OFF);
    for (size_t x = i; x < (size_t)KK * NN; x += stride) {
        const int j     = (int)(x & 7);
        const int lane  = (int)((x >> 3) & 63);
        const int ktile = (int)((x >> 9) & 3);
        const int ntile = (int)((x >> 11) & 3);
        const int w     = (int)((x >> 13) & 7);
        const int nt    = (int)(x >> 16);
        const int n = nt * 512 + w * 64 + ntile * 16 + (lane & 15);
        const int k = ktile * 32 + ((lane >> 4) << 3) + j;
        EtSw[x] = (_Float16)enc[(size_t)n * KK + k];
    }
    // SdSw: decode B-fragments, FULL-K ownership (R12-verified layout).
    _Float16* SdSw = (_Float16*)(ws + SDSW_OFF);
    for (size_t x = i; x < (size_t)NN * DS; x += stride) {
        const int j     = (int)(x & 7);
        const int lane  = (int)((x >> 3) & 63);
        const int ktile = (int)((x >> 9) & 15);
        const int cg    = (int)((x >> 13) & 3);
        const int nt    = (int)(x >> 15);
        const int n = nt * 512 + ktile * 32 + ((lane >> 4) << 3) + j;
        const int c = cg * 16 + (lane & 15);
        SdSw[x] = (_Float16)sd[(size_t)n * DS + c];
    }
    for (size_t x = i; x < (size_t)B_ * DOUT; x += stride) out[x] = 0.0f;
}

// R7 chassis (passed: reg-u prefetch, no B3) + sc0 dual-publish exchange.
__global__ __launch_bounds__(THREADS, 1) void persist_kernel(
    const float* __restrict__ seq,          // [B][T][DIN]
    const _Float16* __restrict__ EtSw,      // encoder B-fragments
    const _Float16* __restrict__ SdSw,      // state-decoder B-fragments
    const float* __restrict__ bias,
    const float* __restrict__ gain,
    const float* __restrict__ dec,          // [NN][DOUT]
    unsigned long long* __restrict__ psqA,  // agent tagged [2][BTILES][NTILES][BT][DS]
    unsigned long long* __restrict__ psqF,  // sc0 tagged, same layout
    float* __restrict__ out)
{
    __shared__ _Float16 xh[16][136];  // s-half live (cols 64..127); rows 8..15 zero
    __shared__ _Float16 Ash[16][520]; // activations f16 (A-operand for decode)

    const int tid = threadIdx.x;
    // XCD-clique swizzle: clique (bt, nt=0..3) shares blockIdx%8.
    const int r8 = blockIdx.x & 7;
    const int s  = blockIdx.x >> 3;
    const int nt = s & 3;
    const int bt = r8 * 8 + (s >> 2);      // 0..63, bijective
    const int n0 = nt * NT;
    const int b0 = bt * BT;

    const int w = tid >> 6;            // wave 0..7
    const int l = tid & 63;
    const int rs = tid >> 6;           // fan-in row 0..7
    const int cs = tid & 63;           // fan-in col
    const int m16 = l & 15;            // fragment row/col index
    const int q8  = (l >> 4) << 3;     // fragment k sub-offset

    const _Float16* EtW = EtSw + ((size_t)(nt * 8 + w) << 13);
    const _Float16* SdW = SdSw + ((size_t)(nt * 4 + (w & 3)) << 13);

    // ---- register-resident weight fragments (loaded once) ----
    half8 etf[4][4];   // [ntile][ktile]
    #pragma unroll
    for (int n4 = 0; n4 < 4; ++n4)
        #pragma unroll
        for (int kt = 0; kt < 4; ++kt)
            etf[n4][kt] = *(const half8*)&EtW[(n4 << 11) + (kt << 9) + (size_t)l * 8];
    half8 sdf[16];     // full-K decode fragments (used by waves 0..3)
    #pragma unroll
    for (int kt = 0; kt < 16; ++kt)
        sdf[kt] = *(const half8*)&SdW[(kt << 9) + (size_t)l * 8];

    // epilogue params
    float gv[4], bv[4];
    #pragma unroll
    for (int n4 = 0; n4 < 4; ++n4) {
        gv[n4] = gain[n0 + w * 64 + n4 * 16 + m16];
        bv[n4] = bias[n0 + w * 64 + n4 * 16 + m16];
    }

    // fan-in base: this thread's 4 partials (p = 0..3), stride BT*DS u64s
    const size_t fan_base = ((size_t)bt * NTILES) * BT * DS + (size_t)rs * DS + cs;

    // preamble: zero xh (rows 8..15 of s-half must stay zero)
    {
        unsigned int* xz = (unsigned int*)&xh[0][0];
        for (int i2 = tid; i2 < 16 * 136 / 2; i2 += THREADS) xz[i2] = 0u;
    }
    __syncthreads();

    // per-lane u prefetch registers (A-fragment source); rows 8..15 -> zero
    float4 u0a = {0.f,0.f,0.f,0.f}, u0b = {0.f,0.f,0.f,0.f};
    float4 u1a = {0.f,0.f,0.f,0.f}, u1b = {0.f,0.f,0.f,0.f};
    if (m16 < 8) {
        const float* up = &seq[((size_t)(b0 + m16) * T_ + 0) * DIN];
        u0a = *(const float4*)&up[q8];
        u0b = *(const float4*)&up[q8 + 4];
        u1a = *(const float4*)&up[32 + q8];
        u1b = *(const float4*)&up[32 + q8 + 4];
    }

    int fastfails = 0;
    int slowmode  = 0;   // sticky: 2 fallbacks -> permanent R0 agent mode

    for (int t = 0; t < T_; ++t) {
        const size_t par = (size_t)((t - 1) & 1);
        const unsigned long long* pbF = psqF + par * PSQ_ELEMS + fan_base;
        const unsigned long long* pbA = psqA + par * PSQ_ELEMS + fan_base;
        unsigned long long v0 = 0, v1 = 0, v2 = 0, v3 = 0;
        // ---- speculative poll issue: loads in flight during encode-A ----
        if (t > 0) {
            if (slowmode == 0) {
                asm volatile("global_load_dwordx2 %0, %4, off sc0\n\t"
                             "global_load_dwordx2 %1, %5, off sc0\n\t"
                             "global_load_dwordx2 %2, %6, off sc0\n\t"
                             "global_load_dwordx2 %3, %7, off sc0"
                             : "=&v"(v0), "=&v"(v1), "=&v"(v2), "=&v"(v3)
                             : "v"(pbF + 0 * (BT * DS)), "v"(pbF + 1 * (BT * DS)),
                               "v"(pbF + 2 * (BT * DS)), "v"(pbF + 3 * (BT * DS))
                             : "memory");
            } else {
                v0 = __hip_atomic_load(pbA + 0 * (BT * DS), __ATOMIC_RELAXED, __HIP_MEMORY_SCOPE_AGENT);
                v1 = __hip_atomic_load(pbA + 1 * (BT * DS), __ATOMIC_RELAXED, __HIP_MEMORY_SCOPE_AGENT);
                v2 = __hip_atomic_load(pbA + 2 * (BT * DS), __ATOMIC_RELAXED, __HIP_MEMORY_SCOPE_AGENT);
                v3 = __hip_atomic_load(pbA + 3 * (BT * DS), __ATOMIC_RELAXED, __HIP_MEMORY_SCOPE_AGENT);
            }
        }

        // ---- build encode-A A-fragments from prefetched u(t) registers ----
        half8 af0, af1;
        af0[0] = (_Float16)u0a.x; af0[1] = (_Float16)u0a.y;
        af0[2] = (_Float16)u0a.z; af0[3] = (_Float16)u0a.w;
        af0[4] = (_Float16)u0b.x; af0[5] = (_Float16)u0b.y;
        af0[6] = (_Float16)u0b.z; af0[7] = (_Float16)u0b.w;
        af1[0] = (_Float16)u1a.x; af1[1] = (_Float16)u1a.y;
        af1[2] = (_Float16)u1a.z; af1[3] = (_Float16)u1a.w;
        af1[4] = (_Float16)u1b.x; af1[5] = (_Float16)u1b.y;
        af1[6] = (_Float16)u1b.z; af1[7] = (_Float16)u1b.w;

        // ---- issue u(t+1) prefetch now (~full step of latency cover) ----
        if (m16 < 8 && t + 1 < T_) {
            const float* up = &seq[((size_t)(b0 + m16) * T_ + (t + 1)) * DIN];
            u0a = *(const float4*)&up[q8];
            u0b = *(const float4*)&up[q8 + 4];
            u1a = *(const float4*)&up[32 + q8];
            u1b = *(const float4*)&up[32 + q8 + 4];
        }

        // ---- encode phase A: k-tiles 0,1 (register A-operand) ----
        f32x4 acc[4];
        #pragma unroll
        for (int n4 = 0; n4 < 4; ++n4) acc[n4] = (f32x4){0.f, 0.f, 0.f, 0.f};
        #pragma unroll
        for (int n4 = 0; n4 < 4; ++n4) {
            acc[n4] = __builtin_amdgcn_mfma_f32_16x16x32_f16(af0, etf[n4][0], acc[n4], 0, 0, 0);
            acc[n4] = __builtin_amdgcn_mfma_f32_16x16x32_f16(af1, etf[n4][1], acc[n4], 0, 0, 0);
        }

        // ---- acquire s(t-1) ----
        if (t > 0) {
            const unsigned utag = (unsigned)t;
            if (slowmode == 0) {
                // wait for speculative sc0 loads; "+v" in/outs make the wait
                // the def point of v0..v3 (rule #18), sched fence after.
                asm volatile("s_waitcnt vmcnt(0)"
                             : "+v"(v0), "+v"(v1), "+v"(v2), "+v"(v3) :: "memory");
                __builtin_amdgcn_sched_barrier(0);
                bool allf = ((unsigned)(v0 >> 32) == utag) & ((unsigned)(v1 >> 32) == utag)
                          & ((unsigned)(v2 >> 32) == utag) & ((unsigned)(v3 >> 32) == utag);
                if (!__all(allf)) {
                    bool fb = false;
                    // sentinel spin: slot 0 only, 8B/lane/retry (anti-convoy)
                    int it = 0;
                    while (!__all((unsigned)(v0 >> 32) == utag)) {
                        if (++it > 24) { fb = true; break; }
                        asm volatile("global_load_dwordx2 %0, %1, off sc0\n\t"
                                     "s_waitcnt vmcnt(0)"
                                     : "=v"(v0) : "v"(pbF + 0 * (BT * DS)) : "memory");
                        __builtin_amdgcn_sched_barrier(0);
                    }
                    if (!fb) {
                        // slots 1..3: written at the same instant; usually
                        // fresh on the first refresh.
                        it = 0;
                        for (;;) {
                            asm volatile("global_load_dwordx2 %0, %3, off sc0\n\t"
                                         "global_load_dwordx2 %1, %4, off sc0\n\t"
                                         "global_load_dwordx2 %2, %5, off sc0\n\t"
                                         "s_waitcnt vmcnt(0)"
                                         : "=&v"(v1), "=&v"(v2), "=&v"(v3)
                                         : "v"(pbF + 1 * (BT * DS)),
                                           "v"(pbF + 2 * (BT * DS)),
                                           "v"(pbF + 3 * (BT * DS))
                                         : "memory");
                            __builtin_amdgcn_sched_barrier(0);
                            if (__all(((unsigned)(v1 >> 32) == utag)
                                    & ((unsigned)(v2 >> 32) == utag)
                                    & ((unsigned)(v3 >> 32) == utag))) break;
                            if (++it > 16) { fb = true; break; }
                        }
                    }
                    if (fb) {
                        // placement-independent fallback: R0 agent loop
                        for (;;) {
                            v0 = __hip_atomic_load(pbA + 0 * (BT * DS), __ATOMIC_RELAXED, __HIP_MEMORY_SCOPE_AGENT);
                            v1 = __hip_atomic_load(pbA + 1 * (BT * DS), __ATOMIC_RELAXED, __HIP_MEMORY_SCOPE_AGENT);
                            v2 = __hip_atomic_load(pbA + 2 * (BT * DS), __ATOMIC_RELAXED, __HIP_MEMORY_SCOPE_AGENT);
                            v3 = __hip_atomic_load(pbA + 3 * (BT * DS), __ATOMIC_RELAXED, __HIP_MEMORY_SCOPE_AGENT);
                            if ((unsigned)(v0 >> 32) == utag && (unsigned)(v1 >> 32) == utag &&
                                (unsigned)(v2 >> 32) == utag && (unsigned)(v3 >> 32) == utag)
                                break;
                        }
                        if (++fastfails >= 2) slowmode = 1;   // sticky
                    }
                }
            } else {
                // permanent R0 agent mode
                for (;;) {
                    if ((unsigned)(v0 >> 32) == utag && (unsigned)(v1 >> 32) == utag &&
                        (unsigned)(v2 >> 32) == utag && (unsigned)(v3 >> 32) == utag)
                        break;
                    v0 = __hip_atomic_load(pbA + 0 * (BT * DS), __ATOMIC_RELAXED, __HIP_MEMORY_SCOPE_AGENT);
                    v1 = __hip_atomic_load(pbA + 1 * (BT * DS), __ATOMIC_RELAXED, __HIP_MEMORY_SCOPE_AGENT);
                    v2 = __hip_atomic_load(pbA + 2 * (BT * DS), __ATOMIC_RELAXED, __HIP_MEMORY_SCOPE_AGENT);
                    v3 = __hip_atomic_load(pbA + 3 * (BT * DS), __ATOMIC_RELAXED, __HIP_MEMORY_SCOPE_AGENT);
                }
            }
            const float ssum = __uint_as_float((unsigned)v0) + __uint_as_float((unsigned)v1)
                             + __uint_as_float((unsigned)v2) + __uint_as_float((unsigned)v3);
            xh[rs][DIN + cs] = (_Float16)ssum;
        } else {
            xh[rs][DIN + cs] = (_Float16)0.f;
        }
        __syncthreads();   // B1: state half ready

        // ---- encode phase B: k-tiles 2,3 (s-half from LDS) ----
        {
            const half8 af2 = *(const half8*)&xh[m16][64 + q8];
            const half8 af3 = *(const half8*)&xh[m16][96 + q8];
            #pragma unroll
            for (int n4 = 0; n4 < 4; ++n4) {
                acc[n4] = __builtin_amdgcn_mfma_f32_16x16x32_f16(af2, etf[n4][2], acc[n4], 0, 0, 0);
                acc[n4] = __builtin_amdgcn_mfma_f32_16x16x32_f16(af3, etf[n4][3], acc[n4], 0, 0, 0);
            }
        }

        // ---- epilogue: rows 0..7 live in lanes 0..31 (row=(l>>4)*4+reg) ----
        if (l < 32) {
            const int rq = (l >> 4) << 2;
            #pragma unroll
            for (int n4 = 0; n4 < 4; ++n4) {
                const int n = w * 64 + n4 * 16 + m16;
                Ash[rq + 0][n] = (_Float16)fabsf(gv[n4] * acc[n4][0] + bv[n4]);
                Ash[rq + 1][n] = (_Float16)fabsf(gv[n4] * acc[n4][1] + bv[n4]);
                Ash[rq + 2][n] = (_Float16)fabsf(gv[n4] * acc[n4][2] + bv[n4]);
                Ash[rq + 3][n] = (_Float16)fabsf(gv[n4] * acc[n4][3] + bv[n4]);
            }
        }
        __syncthreads();   // B2: activations ready

        if (t == T_ - 1) {
            // ---- final projection: out += A_tile @ dec_tile ----
            for (int idx = tid; idx < BT * DOUT; idx += THREADS) {
                const int r = idx / DOUT;
                const int d = idx % DOUT;
                float o = 0.f;
                #pragma unroll 8
                for (int n = 0; n < NT; ++n)
                    o += (float)Ash[r][n] * dec[(size_t)(n0 + n) * DOUT + d];
                atomicAdd(&out[(size_t)(b0 + r) * DOUT + d], o);
            }
            return;
        }

        // ---- decode (waves 0-3, full K=512); waves 4-7 run ahead ----
        if (w < 4) {
            f32x4 d0 = (f32x4){0.f, 0.f, 0.f, 0.f};
            f32x4 d1 = (f32x4){0.f, 0.f, 0.f, 0.f};
            #pragma unroll
            for (int kt = 0; kt < 16; kt += 2) {
                const half8 a0 = *(const half8*)&Ash[m16][kt * 32 + q8];
                d0 = __builtin_amdgcn_mfma_f32_16x16x32_f16(a0, sdf[kt], d0, 0, 0, 0);
                const half8 a1 = *(const half8*)&Ash[m16][(kt + 1) * 32 + q8];
                d1 = __builtin_amdgcn_mfma_f32_16x16x32_f16(a1, sdf[kt + 1], d1, 0, 0, 0);
            }
            d0[0] += d1[0]; d0[1] += d1[1]; d0[2] += d1[2]; d0[3] += d1[3];
            // C/D: col = lane&15 -> state col 16w+m16; rows 0..7 in lanes 0..31
            if (l < 32) {
                const int rq = (l >> 4) << 2;
                const size_t slot = (size_t)(t & 1) * PSQ_ELEMS
                    + (((size_t)bt * NTILES + nt) * BT) * DS + 16 * w + m16;
                unsigned long long* pwF = psqF + slot;
                unsigned long long* pwA = psqA + slot;
                const unsigned long long tg = (unsigned long long)(unsigned)(t + 1) << 32;
                unsigned long long vals[4];
                #pragma unroll
                for (int r = 0; r < 4; ++r)
                    vals[r] = tg | (unsigned long long)__float_as_uint(d0[r]);
                // fast copies first (sc0 -> local L2, earliest visibility)
                #pragma unroll
                for (int r = 0; r < 4; ++r)
                    asm volatile("global_store_dwordx2 %0, %1, off sc0"
                                 :: "v"(pwF + (size_t)(rq + r) * DS), "v"(vals[r])
                                 : "memory");
                // agent mirror (R0's exact stores) for fallback consumers;
                // acks drain inside the next acquire's wait (R7: not exposed)
                #pragma unroll
                for (int r = 0; r < 4; ++r)
                    __hip_atomic_store(pwA + (size_t)(rq + r) * DS, vals[r],
                                       __ATOMIC_RELAXED, __HIP_MEMORY_SCOPE_AGENT);
            }
        }
        // NO B3 (R7-verified): Ash reads(t) < B1(t+1) < Ash writes(t+1);
        // xh writes(t+1) after B2(t); u-path is register-only.
    }
}

extern "C" void kernel_launch(void* const* d_in, const int* in_sizes, int n_in,
                              void* d_out, int out_size, void* d_ws, size_t ws_size,
                              hipStream_t stream) {
    const float* seq  = (const float*)d_in[0];
    const float* enc  = (const float*)d_in[1];
    const float* bias = (const float*)d_in[2];
    const float* gain = (const float*)d_in[3];
    const float* sd   = (const float*)d_in[4];
    const float* dec  = (const float*)d_in[5];
    float* out = (float*)d_out;
    float* ws  = (float*)d_ws;   // psqA (2MB) | psqF (2MB) | EtSw | SdSw

    pre_kernel<<<dim3(1024), dim3(256), 0, stream>>>(enc, sd, ws, out);

    unsigned long long* psqA = (unsigned long long*)ws;
    unsigned long long* psqF = (unsigned long long*)(ws + PSQF_OFF);
    const _Float16* EtSw = (const _Float16*)(ws + ETSW_OFF);
    const _Float16* SdSw = (const _Float16*)(ws + SDSW_OFF);

    persist_kernel<<<dim3(NWG), dim3(THREADS), 0, stream>>>(
        seq, EtSw, SdSw, bias, gain, dec, psqA, psqF, out);
}

// Round 10
// 609.819 us; speedup vs baseline: 1.1543x; 1.1543x over previous
//
#include <hip/hip_runtime.h>
#include <math.h>

// Problem constants
#define B_    512
#define T_    256
#define DIN   64
#define DS    64
#define KK    128   // DIN + DS
#define NN    2048
#define DOUT  10

// Tiling: 256 WGs = NTILES(4) x BTILES(64), 512 thr (8 waves), 1 WG/CU.
#define NT      512
#define BT      8
#define NTILES  (NN / NT)      // 4
#define BTILES  (B_ / BT)      // 64
#define THREADS 512
#define NWG     (NTILES * BTILES)   // 256

// Workspace: psq (u64 tagged partials, double-buffered) | EtSw | SdSw
#define PSQ_ELEMS  ((size_t)BTILES * NTILES * BT * DS)  // 131072 u64 per buffer
#define PS_FLOATS  (4 * PSQ_ELEMS)                      // 2 buffers as float count
#define ETSW_OFF   PS_FLOATS
#define ETSW_F16   ((size_t)KK * NN)                    // 262144 f16 = 512 KB
#define SDSW_OFF   (ETSW_OFF + ETSW_F16 / 2)
#define SDSW_F16   ((size_t)NN * DS)                    // 131072 f16 = 256 KB

typedef _Float16 half8 __attribute__((ext_vector_type(8)));
typedef float    f32x4 __attribute__((ext_vector_type(4)));

__global__ __launch_bounds__(256) void pre_kernel(const float* __restrict__ enc,
                                                  const float* __restrict__ sd,
                                                  float* __restrict__ ws,
                                                  float* __restrict__ out) {
    size_t i = (size_t)blockIdx.x * blockDim.x + threadIdx.x;
    size_t stride = (size_t)gridDim.x * blockDim.x;
    // zero tagged-partial buffers (tag 0 never matches: consumer tags >= 1)
    unsigned long long* psq = (unsigned long long*)ws;
    for (size_t x = i; x < 2 * PSQ_ELEMS; x += stride) psq[x] = 0ull;
    // EtSw: B-fragments, 8-wave ownership (R13-verified).
    _Float16* EtSw = (_Float16*)(ws + ETSW_OFF);
    for (size_t x = i; x < (size_t)KK * NN; x += stride) {
        const int j     = (int)(x & 7);
        const int lane  = (int)((x >> 3) & 63);
        const int ktile = (int)((x >> 9) & 3);
        const int ntile = (int)((x >> 11) & 3);
        const int w     = (int)((x >> 13) & 7);
        const int nt    = (int)(x >> 16);
        const int n = nt * 512 + w * 64 + ntile * 16 + (lane & 15);
        const int k = ktile * 32 + ((lane >> 4) << 3) + j;
        EtSw[x] = (_Float16)enc[(size_t)n * KK + k];
    }
    // SdSw: decode B-fragments, FULL-K ownership (R12-verified layout):
    // per (nt,cg): 16 ktiles x 64 lanes x 8. n = nt*512 + ktile*32 + (lane>>4)*8 + j,
    // c = cg*16 + (lane&15).
    _Float16* SdSw = (_Float16*)(ws + SDSW_OFF);
    for (size_t x = i; x < (size_t)NN * DS; x += stride) {
        const int j     = (int)(x & 7);
        const int lane  = (int)((x >> 3) & 63);
        const int ktile = (int)((x >> 9) & 15);
        const int cg    = (int)((x >> 13) & 3);
        const int nt    = (int)(x >> 15);
        const int n = nt * 512 + ktile * 32 + ((lane >> 4) << 3) + j;
        const int c = cg * 16 + (lane & 15);
        SdSw[x] = (_Float16)sd[(size_t)n * DS + c];
    }
    for (size_t x = i; x < (size_t)B_ * DOUT; x += stride) out[x] = 0.0f;
}

// R17 core (tagged-payload exchange, 556us steady — the 10-round session
// optimum) with 3 chain cuts:
//  1. full-K decode on waves 0-3 (16 MFMA, R12 shape) — Dp reduce deleted.
//  2. waves 4-7 stage u_{t+1} during decode — loop-top barrier deleted.
//  3. speculative poll: tagged loads ISSUED before encode-A, tag check after.
// Tag+payload share one u64 -> every consumed word self-validates; this is
// the ONLY exchange discipline that survived the session (R4/R5/R6/R9
// variants that separated validity from data all hung or corrupted).
// Latency floor arithmetic (R0..R9 measured): agent RTT ~1700-2000cyc;
// step = compute(~800) + commit(~900) + detect quantization(~900) +
// return(~900) + barrier overhead(~700) ~= 5200cyc = 2.17us — as measured.
// sc0/L2-local exchange (R8, fast path verified engaged) measured SLOWER;
// clique-of-4 is forced by the 768KB register-resident weight footprint.
__global__ __launch_bounds__(THREADS, 1) void persist_kernel(
    const float* __restrict__ seq,          // [B][T][DIN]
    const _Float16* __restrict__ EtSw,      // encoder B-fragments
    const _Float16* __restrict__ SdSw,      // state-decoder B-fragments
    const float* __restrict__ bias,
    const float* __restrict__ gain,
    const float* __restrict__ dec,          // [NN][DOUT]
    unsigned long long* __restrict__ psq,   // [2][BTILES][NTILES][BT][DS] tagged
    float* __restrict__ out)
{
    __shared__ _Float16 xh[16][136];  // x_aug f16 (A-operand), rows 8..15 zero
    __shared__ _Float16 Ash[16][520]; // activations f16 (A-operand for decode)

    const int tid = threadIdx.x;
    const int nt = blockIdx.x & (NTILES - 1);
    const int bt = blockIdx.x >> 2;
    const int n0 = nt * NT;
    const int b0 = bt * BT;

    const int w = tid >> 6;            // wave 0..7
    const int l = tid & 63;
    const int rs = tid >> 6;           // fan-in row 0..7
    const int cs = tid & 63;           // fan-in col
    const int m16 = l & 15;            // fragment row/col index
    const int q8  = (l >> 4) << 3;     // fragment k sub-offset

    const _Float16* EtW = EtSw + ((size_t)(nt * 8 + w) << 13);
    const _Float16* SdW = SdSw + ((size_t)(nt * 4 + (w & 3)) << 13);

    // ---- register-resident weight fragments (loaded once) ----
    half8 etf[4][4];   // [ntile][ktile]
    #pragma unroll
    for (int n4 = 0; n4 < 4; ++n4)
        #pragma unroll
        for (int kt = 0; kt < 4; ++kt)
            etf[n4][kt] = *(const half8*)&EtW[(n4 << 11) + (kt << 9) + (size_t)l * 8];
    half8 sdf[16];     // full-K decode fragments (used by waves 0..3)
    #pragma unroll
    for (int kt = 0; kt < 16; ++kt)
        sdf[kt] = *(const half8*)&SdW[(kt << 9) + (size_t)l * 8];

    // epilogue params
    float gv[4], bv[4];
    #pragma unroll
    for (int n4 = 0; n4 < 4; ++n4) {
        gv[n4] = gain[n0 + w * 64 + n4 * 16 + m16];
        bv[n4] = bias[n0 + w * 64 + n4 * 16 + m16];
    }

    // fan-in base: this thread's 4 partials (p = 0..3), stride BT*DS u64s
    const size_t fan_base = ((size_t)bt * NTILES) * BT * DS + (size_t)rs * DS + cs;

    // preamble: zero xh (rows 8..15 stay zero), stage u_0
    {
        unsigned int* xz = (unsigned int*)&xh[0][0];
        for (int i2 = tid; i2 < 16 * 136 / 2; i2 += THREADS) xz[i2] = 0u;
    }
    __syncthreads();
    if (tid < 128) {
        const int r = tid >> 4, c = (tid & 15) << 2;
        const float4 uv = *(const float4*)&seq[((size_t)(b0 + r) * T_ + 0) * DIN + c];
        _Float16* p = &xh[r][c];
        p[0] = (_Float16)uv.x; p[1] = (_Float16)uv.y;
        p[2] = (_Float16)uv.z; p[3] = (_Float16)uv.w;
    }
    __syncthreads();

    for (int t = 0; t < T_; ++t) {
        // ---- speculative poll issue: loads in flight during encode-A ----
        const unsigned long long* pb =
            psq + (size_t)((t - 1) & 1) * PSQ_ELEMS + fan_base;
        unsigned long long v0 = 0, v1 = 0, v2 = 0, v3 = 0;
        if (t > 0) {
            v0 = __hip_atomic_load(pb + 0 * (BT * DS), __ATOMIC_RELAXED, __HIP_MEMORY_SCOPE_AGENT);
            v1 = __hip_atomic_load(pb + 1 * (BT * DS), __ATOMIC_RELAXED, __HIP_MEMORY_SCOPE_AGENT);
            v2 = __hip_atomic_load(pb + 2 * (BT * DS), __ATOMIC_RELAXED, __HIP_MEMORY_SCOPE_AGENT);
            v3 = __hip_atomic_load(pb + 3 * (BT * DS), __ATOMIC_RELAXED, __HIP_MEMORY_SCOPE_AGENT);
        }

        // ---- encode phase A: k-tiles 0,1 (u_t staged last step; no barrier) ----
        f32x4 acc[4];
        #pragma unroll
        for (int n4 = 0; n4 < 4; ++n4) acc[n4] = (f32x4){0.f, 0.f, 0.f, 0.f};
        {
            const half8 af0 = *(const half8*)&xh[m16][q8];
            const half8 af1 = *(const half8*)&xh[m16][32 + q8];
            #pragma unroll
            for (int n4 = 0; n4 < 4; ++n4) {
                acc[n4] = __builtin_amdgcn_mfma_f32_16x16x32_f16(af0, etf[n4][0], acc[n4], 0, 0, 0);
                acc[n4] = __builtin_amdgcn_mfma_f32_16x16x32_f16(af1, etf[n4][1], acc[n4], 0, 0, 0);
            }
        }

        // ---- acquire s(t-1): check speculative values, retry on stale tags ----
        if (t > 0) {
            const unsigned utag = (unsigned)t;
            for (;;) {
                if ((unsigned)(v0 >> 32) == utag && (unsigned)(v1 >> 32) == utag &&
                    (unsigned)(v2 >> 32) == utag && (unsigned)(v3 >> 32) == utag)
                    break;
                v0 = __hip_atomic_load(pb + 0 * (BT * DS), __ATOMIC_RELAXED, __HIP_MEMORY_SCOPE_AGENT);
                v1 = __hip_atomic_load(pb + 1 * (BT * DS), __ATOMIC_RELAXED, __HIP_MEMORY_SCOPE_AGENT);
                v2 = __hip_atomic_load(pb + 2 * (BT * DS), __ATOMIC_RELAXED, __HIP_MEMORY_SCOPE_AGENT);
                v3 = __hip_atomic_load(pb + 3 * (BT * DS), __ATOMIC_RELAXED, __HIP_MEMORY_SCOPE_AGENT);
            }
            const float ssum = __uint_as_float((unsigned)v0) + __uint_as_float((unsigned)v1)
                             + __uint_as_float((unsigned)v2) + __uint_as_float((unsigned)v3);
            xh[rs][DIN + cs] = (_Float16)ssum;
        } else {
            xh[rs][DIN + cs] = (_Float16)0.f;
        }
        __syncthreads();   // B1: state half ready

        // ---- encode phase B: k-tiles 2,3 ----
        {
            const half8 af2 = *(const half8*)&xh[m16][64 + q8];
            const half8 af3 = *(const half8*)&xh[m16][96 + q8];
            #pragma unroll
            for (int n4 = 0; n4 < 4; ++n4) {
                acc[n4] = __builtin_amdgcn_mfma_f32_16x16x32_f16(af2, etf[n4][2], acc[n4], 0, 0, 0);
                acc[n4] = __builtin_amdgcn_mfma_f32_16x16x32_f16(af3, etf[n4][3], acc[n4], 0, 0, 0);
            }
        }

        // ---- epilogue: rows 0..7 live in lanes 0..31 (row=(l>>4)*4+reg) ----
        if (l < 32) {
            const int rq = (l >> 4) << 2;
            #pragma unroll
            for (int n4 = 0; n4 < 4; ++n4) {
                const int n = w * 64 + n4 * 16 + m16;
                Ash[rq + 0][n] = (_Float16)fabsf(gv[n4] * acc[n4][0] + bv[n4]);
                Ash[rq + 1][n] = (_Float16)fabsf(gv[n4] * acc[n4][1] + bv[n4]);
                Ash[rq + 2][n] = (_Float16)fabsf(gv[n4] * acc[n4][2] + bv[n4]);
                Ash[rq + 3][n] = (_Float16)fabsf(gv[n4] * acc[n4][3] + bv[n4]);
            }
        }
        __syncthreads();   // B2: activations ready

        if (t == T_ - 1) {
            // ---- final projection: out += A_tile @ dec_tile ----
            for (int idx = tid; idx < BT * DOUT; idx += THREADS) {
                const int r = idx / DOUT;
                const int d = idx % DOUT;
                float o = 0.f;
                #pragma unroll 8
                for (int n = 0; n < NT; ++n)
                    o += (float)Ash[r][n] * dec[(size_t)(n0 + n) * DOUT + d];
                atomicAdd(&out[(size_t)(b0 + r) * DOUT + d], o);
            }
            return;
        }

        // ---- decode (waves 0-3, full K=512) + u_{t+1} staging (waves 4-7) ----
        if (w < 4) {
            f32x4 d0 = (f32x4){0.f, 0.f, 0.f, 0.f};
            f32x4 d1 = (f32x4){0.f, 0.f, 0.f, 0.f};
            #pragma unroll
            for (int kt = 0; kt < 16; kt += 2) {
                const half8 a0 = *(const half8*)&Ash[m16][kt * 32 + q8];
                d0 = __builtin_amdgcn_mfma_f32_16x16x32_f16(a0, sdf[kt], d0, 0, 0, 0);
                const half8 a1 = *(const half8*)&Ash[m16][(kt + 1) * 32 + q8];
                d1 = __builtin_amdgcn_mfma_f32_16x16x32_f16(a1, sdf[kt + 1], d1, 0, 0, 0);
            }
            d0[0] += d1[0]; d0[1] += d1[1]; d0[2] += d1[2]; d0[3] += d1[3];
            // C/D: col = lane&15 -> state col 16w+m16; rows 0..7 in lanes 0..31
            if (l < 32) {
                const int rq = (l >> 4) << 2;
                unsigned long long* pw = psq + (size_t)(t & 1) * PSQ_ELEMS
                    + (((size_t)bt * NTILES + nt) * BT) * DS + 16 * w + m16;
                const unsigned long long tg = (unsigned long long)(unsigned)(t + 1) << 32;
                #pragma unroll
                for (int r = 0; r < 4; ++r) {
                    __hip_atomic_store(pw + (size_t)(rq + r) * DS,
                                       tg | (unsigned long long)__float_as_uint(d0[r]),
                                       __ATOMIC_RELAXED, __HIP_MEMORY_SCOPE_AGENT);
                }
            }
        } else if (l < 32) {
            // stage u_{t+1}: 4 waves x 32 lanes = 128 float4 loads
            const int idx = ((w - 4) << 5) + l;     // 0..127
            const int r = idx >> 4, c = (idx & 15) << 2;
            const float4 uv =
                *(const float4*)&seq[((size_t)(b0 + r) * T_ + (t + 1)) * DIN + c];
            _Float16* p = &xh[r][c];
            p[0] = (_Float16)uv.x; p[1] = (_Float16)uv.y;
            p[2] = (_Float16)uv.z; p[3] = (_Float16)uv.w;
        }
        __syncthreads();   // B3: decode reads of Ash done + u_{t+1} staged
        // no drain, no counter — tag rides with the data
    }
}

extern "C" void kernel_launch(void* const* d_in, const int* in_sizes, int n_in,
                              void* d_out, int out_size, void* d_ws, size_t ws_size,
                              hipStream_t stream) {
    const float* seq  = (const float*)d_in[0];
    const float* enc  = (const float*)d_in[1];
    const float* bias = (const float*)d_in[2];
    const float* gain = (const float*)d_in[3];
    const float* sd   = (const float*)d_in[4];
    const float* dec  = (const float*)d_in[5];
    float* out = (float*)d_out;
    float* ws  = (float*)d_ws;   // psq[2] (2 MB) | EtSw | SdSw  (~2.8 MB)

    pre_kernel<<<dim3(1024), dim3(256), 0, stream>>>(enc, sd, ws, out);

    unsigned long long* psq = (unsigned long long*)ws;
    const _Float16* EtSw = (const _Float16*)(ws + ETSW_OFF);
    const _Float16* SdSw = (const _Float16*)(ws + SDSW_OFF);

    persist_kernel<<<dim3(NWG), dim3(THREADS), 0, stream>>>(
        seq, EtSw, SdSw, bias, gain, dec, psq, out);
}